// Round 2
// baseline (190.679 us; speedup 1.0000x reference)
//
#include <hip/hip_runtime.h>

#define HIDDEN 1024
#define NTOK (8 * 2048)   // B*S = 16384 tokens
#define BM 256
#define BN 256
#define BK 64

typedef __attribute__((ext_vector_type(4))) float f32x4;
typedef __attribute__((ext_vector_type(8))) short bf16x8;
typedef __attribute__((ext_vector_type(4))) unsigned short u16x4;
typedef __attribute__((ext_vector_type(8))) unsigned short u16x8;

typedef __attribute__((address_space(3))) unsigned int lds_u32;
typedef __attribute__((address_space(1))) unsigned int glb_u32;

__device__ inline unsigned short f2b(float f) {
    unsigned int u = __float_as_uint(f);
    u += 0x7fffu + ((u >> 16) & 1u);   // round-to-nearest-even
    return (unsigned short)(u >> 16);
}
__device__ inline float b2f(unsigned short u) {
    return __uint_as_float(((unsigned int)u) << 16);
}

// ---------------- fp32 -> bf16 convert (vectorized, grid-stride) -------------
__global__ __launch_bounds__(256) void cvt_f2b(const float4* __restrict__ in,
                                               u16x4* __restrict__ out, int n4) {
    int stride = gridDim.x * blockDim.x;
    for (int i = blockIdx.x * blockDim.x + threadIdx.x; i < n4; i += stride) {
        float4 x = in[i];
        u16x4 r;
        r[0] = f2b(x.x); r[1] = f2b(x.y); r[2] = f2b(x.z); r[3] = f2b(x.w);
        out[i] = r;
    }
}

// ---------------- fused QKV GEMM, 256x256 8-phase schedule -------------------
// C = X (16384x1024) * W^T + bias ; N dim = 3 matrices x 1024 = 12 n-tiles.
// 512 thr = 8 waves (2M x 4N), per-wave out 128x64, BK=64, 16 K-tiles.
// LDS: 2 dbuf x (A 256x64 + B 256x64) bf16 = 128 KiB, slot^(row&7) swizzle.
__global__ __launch_bounds__(512, 2) void qkv_gemm(
    const unsigned short* __restrict__ Xb,
    const unsigned short* __restrict__ Wb,
    const float* __restrict__ bq, const float* __restrict__ bk,
    const float* __restrict__ bv,
    unsigned short* __restrict__ QKV) {
    __shared__ __align__(16) unsigned short As[2][BM * BK];
    __shared__ __align__(16) unsigned short Bs[2][BN * BK];

    const int tid = threadIdx.x;
    const int lane = tid & 63, wave = tid >> 6;
    const int wm = wave >> 2, wn = wave & 3;      // 2x4 wave grid

    // bijective XCD swizzle: 768 blocks % 8 == 0
    const int bid = blockIdx.x;
    const int swz = (bid & 7) * 96 + (bid >> 3);
    const int mt = swz & 63;                      // 64 m-tiles (fast: share B panel)
    const int nt = swz >> 6;                      // 12 n-tiles
    const int mat = nt >> 2;                      // 0=q 1=k 2=v
    const int col0 = (nt & 3) * BN;
    const int row0 = mt * BM;

    const unsigned short* Ag = Xb + (size_t)row0 * HIDDEN;
    const unsigned short* Bg = Wb + (size_t)mat * (HIDDEN * HIDDEN)
                                  + (size_t)col0 * HIDDEN;
    const float* bias = (mat == 0) ? bq : ((mat == 1) ? bk : bv);
    unsigned short* Out = QKV + (size_t)mat * ((size_t)NTOK * HIDDEN);

    // stage one half-tile (128 rows x 64 cols) = 2 x global_load_lds per thread.
    // LDS dest linear; global source pre-swizzled: ls = ps ^ (row&7).
    auto stage_half = [&](const unsigned short* gbase, unsigned short* lbase,
                          int kb, int half) {
#pragma unroll
        for (int i = 0; i < 2; ++i) {
            const int r = half * 128 + i * 64 + (tid >> 3);
            const int ls = (tid & 7) ^ ((tid >> 3) & 7);
            const unsigned short* src = gbase + (size_t)r * HIDDEN + kb + ls * 8;
            unsigned short* dst = lbase + half * 8192 + i * 4096 + tid * 8;
            __builtin_amdgcn_global_load_lds((const glb_u32*)src, (lds_u32*)dst,
                                             16, 0, 0);
        }
    };

    // ---- prologue: tile0 A+B, tile1 B (A of tile1 comes in phases 1-2 of j=0)
    stage_half(Ag, As[0], 0, 0);
    stage_half(Ag, As[0], 0, 1);
    stage_half(Bg, Bs[0], 0, 0);
    stage_half(Bg, Bs[0], 0, 1);
    stage_half(Bg, Bs[1], BK, 0);
    stage_half(Bg, Bs[1], BK, 1);
    asm volatile("s_waitcnt vmcnt(4)" ::: "memory");  // tile0 landed
    __builtin_amdgcn_s_barrier();

    f32x4 acc[8][4] = {};
    const int fr = lane & 15;
    const int kq = lane >> 4;
    const int fx = fr & 7;

    for (int j = 0; j < 16; ++j) {
        const int cur = j & 1;
        const unsigned short* Abuf = As[cur];
        const unsigned short* Bbuf = Bs[cur];
        const int tA = (j + 1 < 16) ? j + 1 : 15;   // A of tile j+1 -> As[cur^1]
        const int tB = (j + 2 < 16) ? j + 2 : 15;   // B of tile j+2 -> Bs[cur]
        bf16x8 aq[4][2], bq2[2][2][2];

        // ---------- P1: quadrant (mh0,nh0) — read A m0-3, B n0-1 ----------
#pragma unroll
        for (int m = 0; m < 4; ++m)
#pragma unroll
            for (int kh = 0; kh < 2; ++kh) {
                const int r = wm * 128 + m * 16 + fr;
                const int ps = (kh * 4 + kq) ^ fx;
                aq[m][kh] = *(const bf16x8*)(Abuf + r * 64 + ps * 8);
            }
#pragma unroll
        for (int n = 0; n < 2; ++n)
#pragma unroll
            for (int kh = 0; kh < 2; ++kh) {
                const int r = wn * 64 + n * 16 + fr;
                const int ps = (kh * 4 + kq) ^ fx;
                bq2[0][n][kh] = *(const bf16x8*)(Bbuf + r * 64 + ps * 8);
            }
        stage_half(Ag, As[cur ^ 1], tA * BK, 0);
        __builtin_amdgcn_s_barrier();
        asm volatile("s_waitcnt lgkmcnt(0)" ::: "memory");
        __builtin_amdgcn_sched_barrier(0);
        __builtin_amdgcn_s_setprio(1);
#pragma unroll
        for (int m = 0; m < 4; ++m)
#pragma unroll
            for (int n = 0; n < 2; ++n)
#pragma unroll
                for (int kh = 0; kh < 2; ++kh)
                    acc[m][n] = __builtin_amdgcn_mfma_f32_16x16x32_bf16(
                        aq[m][kh], bq2[0][n][kh], acc[m][n], 0, 0, 0);
        __builtin_amdgcn_s_setprio(0);
        __builtin_amdgcn_s_barrier();

        // ---------- P2: (mh0,nh1) — read B n2-3 ----------
#pragma unroll
        for (int n = 0; n < 2; ++n)
#pragma unroll
            for (int kh = 0; kh < 2; ++kh) {
                const int r = wn * 64 + 32 + n * 16 + fr;
                const int ps = (kh * 4 + kq) ^ fx;
                bq2[1][n][kh] = *(const bf16x8*)(Bbuf + r * 64 + ps * 8);
            }
        stage_half(Ag, As[cur ^ 1], tA * BK, 1);
        __builtin_amdgcn_s_barrier();
        asm volatile("s_waitcnt lgkmcnt(0)" ::: "memory");
        __builtin_amdgcn_sched_barrier(0);
        __builtin_amdgcn_s_setprio(1);
#pragma unroll
        for (int m = 0; m < 4; ++m)
#pragma unroll
            for (int n = 0; n < 2; ++n)
#pragma unroll
                for (int kh = 0; kh < 2; ++kh)
                    acc[m][2 + n] = __builtin_amdgcn_mfma_f32_16x16x32_bf16(
                        aq[m][kh], bq2[1][n][kh], acc[m][2 + n], 0, 0, 0);
        __builtin_amdgcn_s_setprio(0);
        __builtin_amdgcn_s_barrier();

        // ---------- P3: (mh1,nh0) — read A m4-7 (B rows of this tile now dead)
#pragma unroll
        for (int m = 0; m < 4; ++m)
#pragma unroll
            for (int kh = 0; kh < 2; ++kh) {
                const int r = wm * 128 + 64 + m * 16 + fr;
                const int ps = (kh * 4 + kq) ^ fx;
                aq[m][kh] = *(const bf16x8*)(Abuf + r * 64 + ps * 8);
            }
        stage_half(Bg, Bs[cur], tB * BK, 0);
        __builtin_amdgcn_s_barrier();
        asm volatile("s_waitcnt lgkmcnt(0)" ::: "memory");
        __builtin_amdgcn_sched_barrier(0);
        __builtin_amdgcn_s_setprio(1);
#pragma unroll
        for (int m = 0; m < 4; ++m)
#pragma unroll
            for (int n = 0; n < 2; ++n)
#pragma unroll
                for (int kh = 0; kh < 2; ++kh)
                    acc[4 + m][n] = __builtin_amdgcn_mfma_f32_16x16x32_bf16(
                        aq[m][kh], bq2[0][n][kh], acc[4 + m][n], 0, 0, 0);
        __builtin_amdgcn_s_setprio(0);
        __builtin_amdgcn_s_barrier();

        // ---------- P4: (mh1,nh1) — no ds_read; counted vmcnt, never 0 ------
        stage_half(Bg, Bs[cur], tB * BK, 1);
        __builtin_amdgcn_s_barrier();
        __builtin_amdgcn_s_setprio(1);
#pragma unroll
        for (int m = 0; m < 4; ++m)
#pragma unroll
            for (int n = 0; n < 2; ++n)
#pragma unroll
                for (int kh = 0; kh < 2; ++kh)
                    acc[4 + m][2 + n] = __builtin_amdgcn_mfma_f32_16x16x32_bf16(
                        aq[m][kh], bq2[1][n][kh], acc[4 + m][2 + n], 0, 0, 0);
        __builtin_amdgcn_s_setprio(0);
        // outstanding: B(j+1)x2, A(j+1)x2, B(j+2)x2 halves = 12 loads;
        // vmcnt(4) completes oldest 8 = tile j+1 fully landed.
        asm volatile("s_waitcnt vmcnt(4)" ::: "memory");
        __builtin_amdgcn_s_barrier();
    }

    // ---- epilogue: bias add, bf16 store. C/D map: col=lane&15, row=(lane>>4)*4+j
    const int fq = lane >> 4;
    float bvv[4];
#pragma unroll
    for (int n = 0; n < 4; ++n) bvv[n] = bias[col0 + wn * 64 + n * 16 + fr];
#pragma unroll
    for (int m = 0; m < 8; ++m) {
#pragma unroll
        for (int n = 0; n < 4; ++n) {
            const int colg = col0 + wn * 64 + n * 16 + fr;
#pragma unroll
            for (int jj = 0; jj < 4; ++jj) {
                const int rowg = row0 + wm * 128 + m * 16 + fq * 4 + jj;
                Out[(size_t)rowg * HIDDEN + colg] = f2b(acc[m][n][jj] + bvv[n]);
            }
        }
    }
}

// ---------------- per-token attention over the HEAD dim ----------------------
// one wave per token; lane = h*8+g computes score[h][g]; softmax over g.
__global__ __launch_bounds__(256) void attn_k(const unsigned short* __restrict__ QKV,
                                              float* __restrict__ out) {
    __shared__ unsigned short sQ[4][HIDDEN];
    __shared__ unsigned short sK[4][HIDDEN];
    __shared__ unsigned short sV[4][HIDDEN];
    __shared__ float sA[4][64];

    const int t = threadIdx.x, lane = t & 63, wave = t >> 6;
    const int token = blockIdx.x * 4 + wave;
    const size_t base = (size_t)token * HIDDEN;
    const unsigned short* q = QKV + base;
    const unsigned short* k = QKV + (size_t)NTOK * HIDDEN + base;
    const unsigned short* v = QKV + 2 * (size_t)NTOK * HIDDEN + base;

#pragma unroll
    for (int i = 0; i < 2; ++i) {
        const int off = (i * 64 + lane) * 8;
        *(u16x8*)&sQ[wave][off] = *(const u16x8*)&q[off];
        *(u16x8*)&sK[wave][off] = *(const u16x8*)&k[off];
        *(u16x8*)&sV[wave][off] = *(const u16x8*)&v[off];
    }
    __syncthreads();

    const int h = lane >> 3, g = lane & 7;
    float sc = 0.f;
    const unsigned short* Qr = &sQ[wave][h * 128];
    const unsigned short* Kr = &sK[wave][g * 128];
#pragma unroll
    for (int d = 0; d < 128; d += 8) {
        u16x8 qv = *(const u16x8*)&Qr[d];
        u16x8 kv = *(const u16x8*)&Kr[d];
#pragma unroll
        for (int j = 0; j < 8; ++j) sc += b2f(qv[j]) * b2f(kv[j]);
    }
    sc *= -0.08838834764831845f;   // NEGATED scale, faithful to source quirk

    float mx = sc;
#pragma unroll
    for (int o = 1; o < 8; o <<= 1) mx = fmaxf(mx, __shfl_xor(mx, o, 64));
    const float e = __expf(sc - mx);
    float sm = e;
#pragma unroll
    for (int o = 1; o < 8; o <<= 1) sm += __shfl_xor(sm, o, 64);
    sA[wave][lane] = e / sm;
    __syncthreads();

    const int c = lane & 7;        // 16-wide d-chunk within head
    float ov[16];
#pragma unroll
    for (int j = 0; j < 16; ++j) ov[j] = 0.f;
    const float* Ar = &sA[wave][h * 8];
#pragma unroll
    for (int gg = 0; gg < 8; ++gg) {
        const float a = Ar[gg];
        const unsigned short* Vr = &sV[wave][gg * 128 + c * 16];
#pragma unroll
        for (int j = 0; j < 16; ++j) ov[j] += a * b2f(Vr[j]);
    }
    float* op = out + base + lane * 16;   // lane*16 == h*128 + c*16
#pragma unroll
    for (int j = 0; j < 16; j += 4) {
        float4 r = make_float4(ov[j], ov[j + 1], ov[j + 2], ov[j + 3]);
        *(float4*)&op[j] = r;
    }
}

extern "C" void kernel_launch(void* const* d_in, const int* in_sizes, int n_in,
                              void* d_out, int out_size, void* d_ws, size_t ws_size,
                              hipStream_t stream) {
    const float* x1 = (const float*)d_in[0];
    const float* Wq = (const float*)d_in[1];
    const float* bq = (const float*)d_in[2];
    const float* Wk = (const float*)d_in[3];
    const float* bk = (const float*)d_in[4];
    const float* Wv = (const float*)d_in[5];
    const float* bv = (const float*)d_in[6];
    float* out = (float*)d_out;

    // workspace layout (bf16 as ushort): Xb | Wb(q,k,v) | QKV  -> 140.5 MB
    unsigned short* Xb  = (unsigned short*)d_ws;
    unsigned short* Wb  = Xb + (size_t)NTOK * HIDDEN;
    unsigned short* QKV = Wb + 3 * (size_t)HIDDEN * HIDDEN;

    cvt_f2b<<<2048, 256, 0, stream>>>((const float4*)x1, (u16x4*)Xb,
                                      NTOK * HIDDEN / 4);
    cvt_f2b<<<512, 256, 0, stream>>>((const float4*)Wq, (u16x4*)Wb,
                                     HIDDEN * HIDDEN / 4);
    cvt_f2b<<<512, 256, 0, stream>>>((const float4*)Wk,
                                     (u16x4*)(Wb + HIDDEN * HIDDEN),
                                     HIDDEN * HIDDEN / 4);
    cvt_f2b<<<512, 256, 0, stream>>>((const float4*)Wv,
                                     (u16x4*)(Wb + 2 * HIDDEN * HIDDEN),
                                     HIDDEN * HIDDEN / 4);

    qkv_gemm<<<dim3(768), 512, 0, stream>>>(Xb, Wb, bq, bk, bv, QKV);

    attn_k<<<NTOK / 4, 256, 0, stream>>>(QKV, out);
}

// Round 3
// 188.320 us; speedup vs baseline: 1.0125x; 1.0125x over previous
//
#include <hip/hip_runtime.h>

#define HIDDEN 1024
#define NTOK (8 * 2048)   // B*S = 16384 tokens
#define BM 256
#define BN 256
#define BK 64

typedef __attribute__((ext_vector_type(4))) float f32x4;
typedef __attribute__((ext_vector_type(8))) short bf16x8;
typedef __attribute__((ext_vector_type(4))) unsigned short u16x4;
typedef __attribute__((ext_vector_type(8))) unsigned short u16x8;

typedef __attribute__((address_space(3))) unsigned int lds_u32;
typedef __attribute__((address_space(1))) unsigned int glb_u32;

__device__ inline unsigned short f2b(float f) {
    unsigned int u = __float_as_uint(f);
    u += 0x7fffu + ((u >> 16) & 1u);   // round-to-nearest-even
    return (unsigned short)(u >> 16);
}
__device__ inline float b2f(unsigned short u) {
    return __uint_as_float(((unsigned int)u) << 16);
}

// ---------------- fp32 -> bf16 convert, all 4 arrays in one launch ----------
__global__ __launch_bounds__(256) void cvt_all(
    const float4* __restrict__ x1, const float4* __restrict__ wq,
    const float4* __restrict__ wk, const float4* __restrict__ wv,
    u16x4* __restrict__ dst) {
    const int NX = NTOK * HIDDEN / 4;       // 4194304
    const int NW = HIDDEN * HIDDEN / 4;     // 262144
    const int total = NX + 3 * NW;
    const int stride = gridDim.x * blockDim.x;
    for (int i = blockIdx.x * blockDim.x + threadIdx.x; i < total; i += stride) {
        const float4* s; int o;
        if (i < NX)               { s = x1; o = i; }
        else if (i < NX + NW)     { s = wq; o = i - NX; }
        else if (i < NX + 2 * NW) { s = wk; o = i - NX - NW; }
        else                      { s = wv; o = i - NX - 2 * NW; }
        float4 x = s[o];
        u16x4 r;
        r[0] = f2b(x.x); r[1] = f2b(x.y); r[2] = f2b(x.z); r[3] = f2b(x.w);
        dst[i] = r;
    }
}

// 8 MFMAs of one quadrant: acc[MH*4+m][NH*2+n] += a[m] x b[n]
template <int MH, int NH>
__device__ inline void mm8(f32x4 (&acc)[8][4], const bf16x8 (&a)[4],
                           const bf16x8 (&b)[2]) {
#pragma unroll
    for (int m = 0; m < 4; ++m)
#pragma unroll
        for (int n = 0; n < 2; ++n)
            acc[MH * 4 + m][NH * 2 + n] = __builtin_amdgcn_mfma_f32_16x16x32_bf16(
                a[m], b[n], acc[MH * 4 + m][NH * 2 + n], 0, 0, 0);
}

// ---------------- fused QKV GEMM, 256x256, derived-waits 8-subphase ---------
// C = X (16384x1024) * W^T + bias ; 12 n-tiles (3 mats x 4), 64 m-tiles.
// 512 thr = 8 waves (2M x 4N), per-wave out 128x64, BK=64, 16 K-tiles.
// Every ds_read issued >=1 phase before its MFMA consumes it (derived waits).
__global__ __launch_bounds__(512, 2) void qkv_gemm(
    const unsigned short* __restrict__ Xb,
    const unsigned short* __restrict__ Wb,
    const float* __restrict__ bqp, const float* __restrict__ bkp,
    const float* __restrict__ bvp,
    unsigned short* __restrict__ QKV) {
    __shared__ __align__(16) unsigned short As[2][BM * BK];
    __shared__ __align__(16) unsigned short Bs[2][BN * BK];

    const int tid = threadIdx.x;
    const int lane = tid & 63, wave = tid >> 6;
    const int wm = wave >> 2, wn = wave & 3;      // 2x4 wave grid

    // bijective XCD swizzle: 768 blocks % 8 == 0
    const int bid = blockIdx.x;
    const int swz = (bid & 7) * 96 + (bid >> 3);
    const int mt = swz & 63;
    const int nt = swz >> 6;
    const int mat = nt >> 2;                      // 0=q 1=k 2=v
    const int col0 = (nt & 3) * BN;
    const int row0 = mt * BM;

    const unsigned short* Ag = Xb + (size_t)row0 * HIDDEN;
    const unsigned short* Bg = Wb + (size_t)mat * (HIDDEN * HIDDEN)
                                  + (size_t)col0 * HIDDEN;
    const float* bias = (mat == 0) ? bqp : ((mat == 1) ? bkp : bvp);
    unsigned short* Out = QKV + (size_t)mat * ((size_t)NTOK * HIDDEN);

    // stage one half-tile (128 rows x 64 cols) = 2 global_load_lds per thread.
    // LDS dest linear; global source pre-swizzled: ls = slot ^ (row&7).
    auto stage_half = [&](const unsigned short* gbase, unsigned short* lbase,
                          int kb, int half) {
#pragma unroll
        for (int i = 0; i < 2; ++i) {
            const int r = half * 128 + i * 64 + (tid >> 3);
            const int ls = (tid & 7) ^ ((tid >> 3) & 7);
            const unsigned short* src = gbase + (size_t)r * HIDDEN + kb + ls * 8;
            unsigned short* dst = lbase + half * 8192 + i * 4096 + tid * 8;
            __builtin_amdgcn_global_load_lds((const glb_u32*)src, (lds_u32*)dst,
                                             16, 0, 0);
        }
    };

    const int fr = lane & 15;
    const int kq = lane >> 4;
    const int fx = fr & 7;
    // A frag (mh,m,kh): row = wm*128 + mh*64 + m*16 + fr, swizzled k-slot
    auto rdA = [&](const unsigned short* buf, int mh, int m, int kh) -> bf16x8 {
        const int r = wm * 128 + mh * 64 + m * 16 + fr;
        const int ps = (kh * 4 + kq) ^ fx;
        return *(const bf16x8*)(buf + r * 64 + ps * 8);
    };
    auto rdB = [&](const unsigned short* buf, int nh, int n, int kh) -> bf16x8 {
        const int r = wn * 64 + nh * 32 + n * 16 + fr;
        const int ps = (kh * 4 + kq) ^ fx;
        return *(const bf16x8*)(buf + r * 64 + ps * 8);
    };

    // ---- prologue: A(0), B(0), B(1); then first-phase operands
    stage_half(Ag, As[0], 0, 0);
    stage_half(Ag, As[0], 0, 1);
    stage_half(Bg, Bs[0], 0, 0);
    stage_half(Bg, Bs[0], 0, 1);
    stage_half(Bg, Bs[1], BK, 0);
    stage_half(Bg, Bs[1], BK, 1);
    asm volatile("s_waitcnt vmcnt(4)" ::: "memory");  // A(0),B(0) landed
    __builtin_amdgcn_s_barrier();

    f32x4 acc[8][4] = {};
    bf16x8 aA[4], aB[4], aC[4], aD[4];   // a03k0, a47k0, a03k1, a47k1
    bf16x8 bA[2], bB[2], bC[2], bD[2];   // b01k0, b23k0, b01k1, b23k1
#pragma unroll
    for (int m = 0; m < 4; ++m) aA[m] = rdA(As[0], 0, m, 0);
#pragma unroll
    for (int n = 0; n < 2; ++n) bA[n] = rdB(Bs[0], 0, n, 0);

    for (int j = 0; j < 16; ++j) {
        const int cur = j & 1;
        const unsigned short* Ac = As[cur];
        const unsigned short* Bc = Bs[cur];
        const unsigned short* An = As[cur ^ 1];
        const unsigned short* Bn = Bs[cur ^ 1];
        unsigned short* Anw = As[cur ^ 1];
        unsigned short* Bnw = Bs[cur];            // B(j+2) reuses parity of j

        // ---- p1: mm(mh0,nh0,k0); issue b23k0; stage A(j+1)h0
        __builtin_amdgcn_sched_barrier(0);
#pragma unroll
        for (int n = 0; n < 2; ++n) bB[n] = rdB(Bc, 1, n, 0);
        if (j < 15) stage_half(Ag, Anw, (j + 1) * BK, 0);
        __builtin_amdgcn_sched_barrier(0);
        __builtin_amdgcn_s_setprio(1);
        mm8<0, 0>(acc, aA, bA);
        __builtin_amdgcn_s_setprio(0);
        __builtin_amdgcn_s_barrier();

        // ---- p2: mm(mh0,nh1,k0); issue a47k0
        __builtin_amdgcn_sched_barrier(0);
#pragma unroll
        for (int m = 0; m < 4; ++m) aB[m] = rdA(Ac, 1, m, 0);
        __builtin_amdgcn_sched_barrier(0);
        __builtin_amdgcn_s_setprio(1);
        mm8<0, 1>(acc, aA, bB);
        __builtin_amdgcn_s_setprio(0);
        __builtin_amdgcn_s_barrier();

        // ---- p3: mm(mh1,nh0,k0); issue a03k1; stage A(j+1)h1
        __builtin_amdgcn_sched_barrier(0);
#pragma unroll
        for (int m = 0; m < 4; ++m) aC[m] = rdA(Ac, 0, m, 1);
        if (j < 15) stage_half(Ag, Anw, (j + 1) * BK, 1);
        __builtin_amdgcn_sched_barrier(0);
        __builtin_amdgcn_s_setprio(1);
        mm8<1, 0>(acc, aB, bA);
        __builtin_amdgcn_s_setprio(0);
        __builtin_amdgcn_s_barrier();

        // ---- p4: mm(mh1,nh1,k0); issue b01k1
        __builtin_amdgcn_sched_barrier(0);
#pragma unroll
        for (int n = 0; n < 2; ++n) bC[n] = rdB(Bc, 0, n, 1);
        __builtin_amdgcn_sched_barrier(0);
        __builtin_amdgcn_s_setprio(1);
        mm8<1, 1>(acc, aB, bB);
        __builtin_amdgcn_s_setprio(0);
        __builtin_amdgcn_s_barrier();

        // ---- p5: mm(mh0,nh0,k1); issue b23k1
        __builtin_amdgcn_sched_barrier(0);
#pragma unroll
        for (int n = 0; n < 2; ++n) bD[n] = rdB(Bc, 1, n, 1);
        __builtin_amdgcn_sched_barrier(0);
        __builtin_amdgcn_s_setprio(1);
        mm8<0, 0>(acc, aC, bC);
        __builtin_amdgcn_s_setprio(0);
        __builtin_amdgcn_s_barrier();

        // ---- p6: mm(mh0,nh1,k1); issue a47k1; stage B(j+2)h0
        __builtin_amdgcn_sched_barrier(0);
#pragma unroll
        for (int m = 0; m < 4; ++m) aD[m] = rdA(Ac, 1, m, 1);
        if (j < 14) stage_half(Bg, Bnw, (j + 2) * BK, 0);
        __builtin_amdgcn_sched_barrier(0);
        __builtin_amdgcn_s_setprio(1);
        mm8<0, 1>(acc, aC, bD);
        __builtin_amdgcn_s_setprio(0);
        __builtin_amdgcn_s_barrier();

        // ---- p7: mm(mh1,nh0,k1); stage B(j+2)h1
        __builtin_amdgcn_sched_barrier(0);
        if (j < 14) stage_half(Bg, Bnw, (j + 2) * BK, 1);
        __builtin_amdgcn_sched_barrier(0);
        __builtin_amdgcn_s_setprio(1);
        mm8<1, 0>(acc, aD, bC);
        __builtin_amdgcn_s_setprio(0);
        __builtin_amdgcn_s_barrier();

        // ---- p8: [vmcnt; barrier; read next tile's a03k0+b01k0]; mm(mh1,nh1,k1)
        if (j < 15) {
            if (j < 14) asm volatile("s_waitcnt vmcnt(4)" ::: "memory");
            else        asm volatile("s_waitcnt vmcnt(0)" ::: "memory");
            __builtin_amdgcn_s_barrier();
            __builtin_amdgcn_sched_barrier(0);
#pragma unroll
            for (int m = 0; m < 4; ++m) aA[m] = rdA(An, 0, m, 0);
#pragma unroll
            for (int n = 0; n < 2; ++n) bA[n] = rdB(Bn, 0, n, 0);
            __builtin_amdgcn_sched_barrier(0);
        }
        __builtin_amdgcn_s_setprio(1);
        mm8<1, 1>(acc, aD, bD);
        __builtin_amdgcn_s_setprio(0);
        __builtin_amdgcn_s_barrier();
    }

    // ---- epilogue: bias add, bf16 store. C/D map: col=lane&15, row=(lane>>4)*4+j
    const int fq = lane >> 4;
    float bvv[4];
#pragma unroll
    for (int n = 0; n < 4; ++n) bvv[n] = bias[col0 + wn * 64 + n * 16 + fr];
#pragma unroll
    for (int m = 0; m < 8; ++m) {
#pragma unroll
        for (int n = 0; n < 4; ++n) {
            const int colg = col0 + wn * 64 + n * 16 + fr;
#pragma unroll
            for (int jj = 0; jj < 4; ++jj) {
                const int rowg = row0 + wm * 128 + m * 16 + fq * 4 + jj;
                Out[(size_t)rowg * HIDDEN + colg] = f2b(acc[m][n][jj] + bvv[n]);
            }
        }
    }
}

// ---------------- per-token attention over the HEAD dim ----------------------
// one wave per token; lane = h*8+g computes score[h][g]; softmax over g.
__global__ __launch_bounds__(256) void attn_k(const unsigned short* __restrict__ QKV,
                                              float* __restrict__ out) {
    __shared__ unsigned short sQ[4][HIDDEN];
    __shared__ unsigned short sK[4][HIDDEN];
    __shared__ unsigned short sV[4][HIDDEN];
    __shared__ float sA[4][64];

    const int t = threadIdx.x, lane = t & 63, wave = t >> 6;
    const int token = blockIdx.x * 4 + wave;
    const size_t base = (size_t)token * HIDDEN;
    const unsigned short* q = QKV + base;
    const unsigned short* k = QKV + (size_t)NTOK * HIDDEN + base;
    const unsigned short* v = QKV + 2 * (size_t)NTOK * HIDDEN + base;

#pragma unroll
    for (int i = 0; i < 2; ++i) {
        const int off = (i * 64 + lane) * 8;
        *(u16x8*)&sQ[wave][off] = *(const u16x8*)&q[off];
        *(u16x8*)&sK[wave][off] = *(const u16x8*)&k[off];
        *(u16x8*)&sV[wave][off] = *(const u16x8*)&v[off];
    }
    __syncthreads();

    const int h = lane >> 3, g = lane & 7;
    float sc = 0.f;
    const unsigned short* Qr = &sQ[wave][h * 128];
    const unsigned short* Kr = &sK[wave][g * 128];
#pragma unroll
    for (int d = 0; d < 128; d += 8) {
        u16x8 qv = *(const u16x8*)&Qr[d];
        u16x8 kv = *(const u16x8*)&Kr[d];
#pragma unroll
        for (int j = 0; j < 8; ++j) sc += b2f(qv[j]) * b2f(kv[j]);
    }
    sc *= -0.08838834764831845f;   // NEGATED scale, faithful to source quirk

    float mx = sc;
#pragma unroll
    for (int o = 1; o < 8; o <<= 1) mx = fmaxf(mx, __shfl_xor(mx, o, 64));
    const float e = __expf(sc - mx);
    float sm = e;
#pragma unroll
    for (int o = 1; o < 8; o <<= 1) sm += __shfl_xor(sm, o, 64);
    sA[wave][lane] = e / sm;
    __syncthreads();

    const int c = lane & 7;        // 16-wide d-chunk within head
    float ov[16];
#pragma unroll
    for (int j = 0; j < 16; ++j) ov[j] = 0.f;
    const float* Ar = &sA[wave][h * 8];
#pragma unroll
    for (int gg = 0; gg < 8; ++gg) {
        const float a = Ar[gg];
        const unsigned short* Vr = &sV[wave][gg * 128 + c * 16];
#pragma unroll
        for (int j = 0; j < 16; ++j) ov[j] += a * b2f(Vr[j]);
    }
    float* op = out + base + lane * 16;   // lane*16 == h*128 + c*16
#pragma unroll
    for (int j = 0; j < 16; j += 4) {
        float4 r = make_float4(ov[j], ov[j + 1], ov[j + 2], ov[j + 3]);
        *(float4*)&op[j] = r;
    }
}

extern "C" void kernel_launch(void* const* d_in, const int* in_sizes, int n_in,
                              void* d_out, int out_size, void* d_ws, size_t ws_size,
                              hipStream_t stream) {
    const float* x1 = (const float*)d_in[0];
    const float* Wq = (const float*)d_in[1];
    const float* bq = (const float*)d_in[2];
    const float* Wk = (const float*)d_in[3];
    const float* bk = (const float*)d_in[4];
    const float* Wv = (const float*)d_in[5];
    const float* bv = (const float*)d_in[6];
    float* out = (float*)d_out;

    // workspace layout (bf16 as ushort): Xb | Wb(q,k,v) | QKV  -> 140.5 MB
    unsigned short* Xb  = (unsigned short*)d_ws;
    unsigned short* Wb  = Xb + (size_t)NTOK * HIDDEN;
    unsigned short* QKV = Wb + 3 * (size_t)HIDDEN * HIDDEN;

    cvt_all<<<2048, 256, 0, stream>>>((const float4*)x1, (const float4*)Wq,
                                      (const float4*)Wk, (const float4*)Wv,
                                      (u16x4*)Xb);

    qkv_gemm<<<dim3(768), 512, 0, stream>>>(Xb, Wb, bq, bk, bv, QKV);

    attn_k<<<NTOK / 4, 256, 0, stream>>>(QKV, out);
}

// Round 4
// 163.746 us; speedup vs baseline: 1.1645x; 1.1501x over previous
//
#include <hip/hip_runtime.h>

#define HIDDEN 1024
#define NTOK (8 * 2048)   // B*S = 16384 tokens
#define BM 256
#define BN 128
#define BK 32
#define NT (HIDDEN / BK)  // 32 K-tiles

typedef __attribute__((ext_vector_type(4))) float f32x4;
typedef __attribute__((ext_vector_type(8))) short bf16x8;
typedef __attribute__((ext_vector_type(4))) unsigned short u16x4;
typedef __attribute__((ext_vector_type(8))) unsigned short u16x8;

typedef __attribute__((address_space(3))) unsigned int lds_u32;
typedef __attribute__((address_space(1))) unsigned int glb_u32;

__device__ inline unsigned short f2b(float f) {
    unsigned int u = __float_as_uint(f);
    u += 0x7fffu + ((u >> 16) & 1u);   // round-to-nearest-even
    return (unsigned short)(u >> 16);
}
__device__ inline float b2f(unsigned short u) {
    return __uint_as_float(((unsigned int)u) << 16);
}

// ---------------- fp32 -> bf16 convert, all 4 arrays in one launch ----------
__global__ __launch_bounds__(256) void cvt_all(
    const float4* __restrict__ x1, const float4* __restrict__ wq,
    const float4* __restrict__ wk, const float4* __restrict__ wv,
    u16x4* __restrict__ dst) {
    const int NX = NTOK * HIDDEN / 4;
    const int NW = HIDDEN * HIDDEN / 4;
    const int total = NX + 3 * NW;
    const int stride = gridDim.x * blockDim.x;
    for (int i = blockIdx.x * blockDim.x + threadIdx.x; i < total; i += stride) {
        const float4* s; int o;
        if (i < NX)               { s = x1; o = i; }
        else if (i < NX + NW)     { s = wq; o = i - NX; }
        else if (i < NX + 2 * NW) { s = wk; o = i - NX - NW; }
        else                      { s = wv; o = i - NX - 2 * NW; }
        float4 x = s[o];
        u16x4 r;
        r[0] = f2b(x.x); r[1] = f2b(x.y); r[2] = f2b(x.z); r[3] = f2b(x.w);
        dst[i] = r;
    }
}

// ---------------- fused QKV GEMM: 256x128 tile, BK=32, 2 blocks/CU ----------
// C = X (16384x1024) * W^T + bias ; 64 m-tiles x 24 n-tiles = 1536 blocks.
// 8 waves (4M x 2N), 64x64 per wave (acc=64 regs -> 4 waves/SIMD possible).
// LDS 48 KB dbuf; 1 barrier per K-tile; co-resident block covers the drain.
// Swizzle: 16B slot ^= (row>>1)&3  -> column frag reads hit all 32 banks.
__global__ __launch_bounds__(512, 4) void qkv_gemm(
    const unsigned short* __restrict__ Xb,
    const unsigned short* __restrict__ Wb,
    const float* __restrict__ bqp, const float* __restrict__ bkp,
    const float* __restrict__ bvp,
    unsigned short* __restrict__ QKV) {
    // per buffer: A 256x32 (16 KB) @ [0..8191], B 128x32 (8 KB) @ [8192..12287]
    __shared__ __align__(16) unsigned short sb[2][12288];

    const int tid = threadIdx.x;
    const int lane = tid & 63, wave = tid >> 6;
    const int wm = wave >> 1, wn = wave & 1;      // 4x2 wave grid, 64x64 each

    // 2D super-tile XCD map: 64 super-tiles of (4 mt x 6 nt) = 24 blocks.
    // XCD x gets super-tiles 8x..8x+7 -> per-tile set A 2MB + B 1.5MB fits L2.
    const int bid = blockIdx.x;
    const int xcd = bid & 7;
    const int i6 = bid >> 3;            // 0..191
    const int st = i6 / 24;             // 0..7
    const int w = i6 % 24;              // 0..23
    const int g = xcd * 8 + st;         // global super-tile 0..63
    const int mt = (g >> 2) * 4 + w / 6;    // 0..63
    const int nt = (g & 3) * 6 + w % 6;     // 0..23
    const int mat = nt >> 3;                // 0=q 1=k 2=v
    const int col0 = (nt & 7) * BN;
    const int row0 = mt * BM;

    const unsigned short* Ag = Xb + (size_t)row0 * HIDDEN;
    const unsigned short* Bg = Wb + (size_t)mat * (HIDDEN * HIDDEN)
                                  + (size_t)col0 * HIDDEN;
    const float* bias = (mat == 0) ? bqp : ((mat == 1) ? bkp : bvp);
    unsigned short* Out = QKV + (size_t)mat * ((size_t)NTOK * HIDDEN);

    // staging: 1536 16B-chunks (A:1024, B:512), 3 per thread.
    // chunk gidx: row = gidx>>2 (A) / (gidx-1024)>>2 (B), slot = gidx&3;
    // source col pre-swizzled: slot ^ ((row>>1)&3); LDS dest linear.
    const unsigned short* srcb[3];
    int dstoff[3];
#pragma unroll
    for (int c = 0; c < 3; ++c) {
        const int gidx = c * 512 + tid;
        const int slot = gidx & 3;
        if (gidx < 1024) {
            const int r = gidx >> 2;
            srcb[c] = Ag + (size_t)r * HIDDEN + (slot ^ ((r >> 1) & 3)) * 8;
        } else {
            const int r = (gidx - 1024) >> 2;
            srcb[c] = Bg + (size_t)r * HIDDEN + (slot ^ ((r >> 1) & 3)) * 8;
        }
        dstoff[c] = gidx * 8;
    }

    // frag read bases (halfword offsets), swizzled k-slot
    const int fr = lane & 15;
    const int kq = lane >> 4;            // 16B slot within 32-elem row
    const int sx = (fr >> 1) & 3;
    const int aoff = (wm * 64 + fr) * BK + ((kq ^ sx) * 8);
    const int boff = 8192 + (wn * 64 + fr) * BK + ((kq ^ sx) * 8);

    // prologue: stage tile 0
#pragma unroll
    for (int c = 0; c < 3; ++c)
        __builtin_amdgcn_global_load_lds((const glb_u32*)(srcb[c]),
                                         (lds_u32*)(&sb[0][0] + dstoff[c]), 16, 0, 0);
    __syncthreads();

    f32x4 acc[4][4] = {};

#pragma unroll 2
    for (int j = 0; j < NT; ++j) {
        // stage next tile into the other buffer (latency hidden under MFMAs)
        if (j + 1 < NT) {
            unsigned short* dbuf = &sb[(j + 1) & 1][0];
#pragma unroll
            for (int c = 0; c < 3; ++c)
                __builtin_amdgcn_global_load_lds(
                    (const glb_u32*)(srcb[c] + (j + 1) * BK),
                    (lds_u32*)(dbuf + dstoff[c]), 16, 0, 0);
        }
        // compute current tile
        const unsigned short* buf = &sb[j & 1][0];
        bf16x8 bfr[4];
#pragma unroll
        for (int n = 0; n < 4; ++n)
            bfr[n] = *(const bf16x8*)(buf + boff + n * (16 * BK));
#pragma unroll
        for (int m = 0; m < 4; ++m) {
            const bf16x8 afr = *(const bf16x8*)(buf + aoff + m * (16 * BK));
#pragma unroll
            for (int n = 0; n < 4; ++n)
                acc[m][n] = __builtin_amdgcn_mfma_f32_16x16x32_bf16(
                    afr, bfr[n], acc[m][n], 0, 0, 0);
        }
        __syncthreads();   // drains vmcnt (stage j+1) + lgkm; other block covers
    }

    // epilogue: bias add, bf16 store. C/D map: col=lane&15, row=(lane>>4)*4+jj
    const int fq = lane >> 4;
    float bvv[4];
#pragma unroll
    for (int n = 0; n < 4; ++n) bvv[n] = bias[col0 + wn * 64 + n * 16 + fr];
#pragma unroll
    for (int m = 0; m < 4; ++m) {
#pragma unroll
        for (int n = 0; n < 4; ++n) {
            const int colg = col0 + wn * 64 + n * 16 + fr;
#pragma unroll
            for (int jj = 0; jj < 4; ++jj) {
                const int rowg = row0 + wm * 64 + m * 16 + fq * 4 + jj;
                Out[(size_t)rowg * HIDDEN + colg] = f2b(acc[m][n][jj] + bvv[n]);
            }
        }
    }
}

// ---------------- per-token attention over the HEAD dim ----------------------
// one wave per token; lane = h*8+g computes score[h][g]; softmax over g.
__global__ __launch_bounds__(256) void attn_k(const unsigned short* __restrict__ QKV,
                                              float* __restrict__ out) {
    __shared__ unsigned short sQ[4][HIDDEN];
    __shared__ unsigned short sK[4][HIDDEN];
    __shared__ unsigned short sV[4][HIDDEN];
    __shared__ float sA[4][64];

    const int t = threadIdx.x, lane = t & 63, wave = t >> 6;
    const int token = blockIdx.x * 4 + wave;
    const size_t base = (size_t)token * HIDDEN;
    const unsigned short* q = QKV + base;
    const unsigned short* k = QKV + (size_t)NTOK * HIDDEN + base;
    const unsigned short* v = QKV + 2 * (size_t)NTOK * HIDDEN + base;

#pragma unroll
    for (int i = 0; i < 2; ++i) {
        const int off = (i * 64 + lane) * 8;
        *(u16x8*)&sQ[wave][off] = *(const u16x8*)&q[off];
        *(u16x8*)&sK[wave][off] = *(const u16x8*)&k[off];
        *(u16x8*)&sV[wave][off] = *(const u16x8*)&v[off];
    }
    __syncthreads();

    const int h = lane >> 3, g = lane & 7;
    float sc = 0.f;
    const unsigned short* Qr = &sQ[wave][h * 128];
    const unsigned short* Kr = &sK[wave][g * 128];
#pragma unroll
    for (int d = 0; d < 128; d += 8) {
        u16x8 qv = *(const u16x8*)&Qr[d];
        u16x8 kv = *(const u16x8*)&Kr[d];
#pragma unroll
        for (int j = 0; j < 8; ++j) sc += b2f(qv[j]) * b2f(kv[j]);
    }
    sc *= -0.08838834764831845f;   // NEGATED scale, faithful to source quirk

    float mx = sc;
#pragma unroll
    for (int o = 1; o < 8; o <<= 1) mx = fmaxf(mx, __shfl_xor(mx, o, 64));
    const float e = __expf(sc - mx);
    float sm = e;
#pragma unroll
    for (int o = 1; o < 8; o <<= 1) sm += __shfl_xor(sm, o, 64);
    sA[wave][lane] = e / sm;
    __syncthreads();

    const int c = lane & 7;        // 16-wide d-chunk within head
    float ov[16];
#pragma unroll
    for (int j = 0; j < 16; ++j) ov[j] = 0.f;
    const float* Ar = &sA[wave][h * 8];
#pragma unroll
    for (int gg = 0; gg < 8; ++gg) {
        const float a = Ar[gg];
        const unsigned short* Vr = &sV[wave][gg * 128 + c * 16];
#pragma unroll
        for (int j = 0; j < 16; ++j) ov[j] += a * b2f(Vr[j]);
    }
    float* op = out + base + lane * 16;   // lane*16 == h*128 + c*16
#pragma unroll
    for (int j = 0; j < 16; j += 4) {
        float4 r = make_float4(ov[j], ov[j + 1], ov[j + 2], ov[j + 3]);
        *(float4*)&op[j] = r;
    }
}

extern "C" void kernel_launch(void* const* d_in, const int* in_sizes, int n_in,
                              void* d_out, int out_size, void* d_ws, size_t ws_size,
                              hipStream_t stream) {
    const float* x1 = (const float*)d_in[0];
    const float* Wq = (const float*)d_in[1];
    const float* bq = (const float*)d_in[2];
    const float* Wk = (const float*)d_in[3];
    const float* bk = (const float*)d_in[4];
    const float* Wv = (const float*)d_in[5];
    const float* bv = (const float*)d_in[6];
    float* out = (float*)d_out;

    // workspace layout (bf16 as ushort): Xb | Wb(q,k,v) | QKV  -> 140.5 MB
    unsigned short* Xb  = (unsigned short*)d_ws;
    unsigned short* Wb  = Xb + (size_t)NTOK * HIDDEN;
    unsigned short* QKV = Wb + 3 * (size_t)HIDDEN * HIDDEN;

    cvt_all<<<2048, 256, 0, stream>>>((const float4*)x1, (const float4*)Wq,
                                      (const float4*)Wk, (const float4*)Wv,
                                      (u16x4*)Xb);

    qkv_gemm<<<dim3(1536), 512, 0, stream>>>(Xb, Wb, bq, bk, bv, QKV);

    attn_k<<<NTOK / 4, 256, 0, stream>>>(QKV, out);
}

// Round 5
// 159.221 us; speedup vs baseline: 1.1976x; 1.0284x over previous
//
#include <hip/hip_runtime.h>

#define HIDDEN 1024
#define NTOK (8 * 2048)   // B*S = 16384 tokens
#define BM 256
#define BN 128
#define BK 32
#define NT (HIDDEN / BK)  // 32 K-tiles

typedef __attribute__((ext_vector_type(4))) float f32x4;
typedef __attribute__((ext_vector_type(8))) short bf16x8;
typedef __attribute__((ext_vector_type(4))) unsigned short u16x4;
typedef __attribute__((ext_vector_type(8))) unsigned short u16x8;

typedef __attribute__((address_space(3))) unsigned int lds_u32;
typedef __attribute__((address_space(1))) unsigned int glb_u32;

__device__ inline unsigned short f2b(float f) {
    unsigned int u = __float_as_uint(f);
    u += 0x7fffu + ((u >> 16) & 1u);   // round-to-nearest-even
    return (unsigned short)(u >> 16);
}
__device__ inline float b2f(unsigned short u) {
    return __uint_as_float(((unsigned int)u) << 16);
}

// ---------------- fp32 -> bf16 convert, all 4 arrays in one launch ----------
__global__ __launch_bounds__(256) void cvt_all(
    const float4* __restrict__ x1, const float4* __restrict__ wq,
    const float4* __restrict__ wk, const float4* __restrict__ wv,
    u16x4* __restrict__ dst) {
    const int NX = NTOK * HIDDEN / 4;
    const int NW = HIDDEN * HIDDEN / 4;
    const int total = NX + 3 * NW;
    const int stride = gridDim.x * blockDim.x;
    for (int i = blockIdx.x * blockDim.x + threadIdx.x; i < total; i += stride) {
        const float4* s; int o;
        if (i < NX)               { s = x1; o = i; }
        else if (i < NX + NW)     { s = wq; o = i - NX; }
        else if (i < NX + 2 * NW) { s = wk; o = i - NX - NW; }
        else                      { s = wv; o = i - NX - 2 * NW; }
        float4 x = s[o];
        u16x4 r;
        r[0] = f2b(x.x); r[1] = f2b(x.y); r[2] = f2b(x.z); r[3] = f2b(x.w);
        dst[i] = r;
    }
}

// ---------------- fused QKV GEMM: 256x128 tile, 4 waves of 128x64 -----------
// C = X (16384x1024) * W^T + bias ; 64 m-tiles x 24 n-tiles = 1536 blocks.
// 4 waves (2M x 2N), 128x64 per wave: 12 ds_reads feed 32 MFMAs (vs 8:16 at
// 64x64) -> 25% less LDS read traffic per FLOP; kernel is DS-pipe-bound.
// LDS 48 KB dbuf; 1 barrier per K-tile; co-resident block covers the drain.
// Swizzle: 16B slot ^= (row>>1)&3  -> frag reads spread evenly over banks.
__global__ __launch_bounds__(256, 2) void qkv_gemm(
    const unsigned short* __restrict__ Xb,
    const unsigned short* __restrict__ Wb,
    const float* __restrict__ bqp, const float* __restrict__ bkp,
    const float* __restrict__ bvp,
    unsigned short* __restrict__ QKV) {
    // per buffer: A 256x32 (16 KB) @ [0..8191], B 128x32 (8 KB) @ [8192..12287]
    __shared__ __align__(16) unsigned short sb[2][12288];

    const int tid = threadIdx.x;
    const int lane = tid & 63, wave = tid >> 6;
    const int wm = wave >> 1, wn = wave & 1;      // 2x2 wave grid, 128x64 each

    // 2D super-tile XCD map: 64 super-tiles of (4 mt x 6 nt) = 24 blocks.
    const int bid = blockIdx.x;
    const int xcd = bid & 7;
    const int i6 = bid >> 3;            // 0..191
    const int st = i6 / 24;             // 0..7
    const int w = i6 % 24;              // 0..23
    const int g = xcd * 8 + st;         // global super-tile 0..63
    const int mt = (g >> 2) * 4 + w / 6;    // 0..63
    const int nt = (g & 3) * 6 + w % 6;     // 0..23
    const int mat = nt >> 3;                // 0=q 1=k 2=v
    const int col0 = (nt & 7) * BN;
    const int row0 = mt * BM;

    const unsigned short* Ag = Xb + (size_t)row0 * HIDDEN;
    const unsigned short* Bg = Wb + (size_t)mat * (HIDDEN * HIDDEN)
                                  + (size_t)col0 * HIDDEN;
    const float* bias = (mat == 0) ? bqp : ((mat == 1) ? bkp : bvp);
    unsigned short* Out = QKV + (size_t)mat * ((size_t)NTOK * HIDDEN);

    // staging: 1536 16B-chunks (A:1024, B:512), 6 per thread (256 thr).
    // source col pre-swizzled: slot ^ ((row>>1)&3); LDS dest linear.
    const unsigned short* srcb[6];
    int dstoff[6];
#pragma unroll
    for (int c = 0; c < 6; ++c) {
        const int gidx = c * 256 + tid;
        const int slot = gidx & 3;
        if (gidx < 1024) {
            const int r = gidx >> 2;
            srcb[c] = Ag + (size_t)r * HIDDEN + (slot ^ ((r >> 1) & 3)) * 8;
        } else {
            const int r = (gidx - 1024) >> 2;
            srcb[c] = Bg + (size_t)r * HIDDEN + (slot ^ ((r >> 1) & 3)) * 8;
        }
        dstoff[c] = gidx * 8;
    }

    // frag read bases (halfword offsets), swizzled k-slot
    const int fr = lane & 15;
    const int kq = lane >> 4;            // 16B slot within 32-elem row
    const int sx = (fr >> 1) & 3;
    const int aoff = (wm * 128 + fr) * BK + ((kq ^ sx) * 8);
    const int boff = 8192 + (wn * 64 + fr) * BK + ((kq ^ sx) * 8);

    // prologue: stage tile 0
#pragma unroll
    for (int c = 0; c < 6; ++c)
        __builtin_amdgcn_global_load_lds((const glb_u32*)(srcb[c]),
                                         (lds_u32*)(&sb[0][0] + dstoff[c]), 16, 0, 0);
    __syncthreads();

    f32x4 acc[8][4] = {};

#pragma unroll 2
    for (int j = 0; j < NT; ++j) {
        // stage next tile into the other buffer
        if (j + 1 < NT) {
            unsigned short* dbuf = &sb[(j + 1) & 1][0];
#pragma unroll
            for (int c = 0; c < 6; ++c)
                __builtin_amdgcn_global_load_lds(
                    (const glb_u32*)(srcb[c] + (j + 1) * BK),
                    (lds_u32*)(dbuf + dstoff[c]), 16, 0, 0);
        }
        // compute current tile: 4 B-frags held, 8 A-frags streamed
        const unsigned short* buf = &sb[j & 1][0];
        bf16x8 bfr[4];
#pragma unroll
        for (int n = 0; n < 4; ++n)
            bfr[n] = *(const bf16x8*)(buf + boff + n * (16 * BK));
#pragma unroll
        for (int m = 0; m < 8; ++m) {
            const bf16x8 afr = *(const bf16x8*)(buf + aoff + m * (16 * BK));
#pragma unroll
            for (int n = 0; n < 4; ++n)
                acc[m][n] = __builtin_amdgcn_mfma_f32_16x16x32_bf16(
                    afr, bfr[n], acc[m][n], 0, 0, 0);
        }
        __syncthreads();   // drains vmcnt (stage j+1); other block covers
    }

    // epilogue: bias add, bf16 store. C/D map: col=lane&15, row=(lane>>4)*4+jj
    const int fq = lane >> 4;
    float bvv[4];
#pragma unroll
    for (int n = 0; n < 4; ++n) bvv[n] = bias[col0 + wn * 64 + n * 16 + fr];
#pragma unroll
    for (int m = 0; m < 8; ++m) {
#pragma unroll
        for (int n = 0; n < 4; ++n) {
            const int colg = col0 + wn * 64 + n * 16 + fr;
#pragma unroll
            for (int jj = 0; jj < 4; ++jj) {
                const int rowg = row0 + wm * 128 + m * 16 + fq * 4 + jj;
                Out[(size_t)rowg * HIDDEN + colg] = f2b(acc[m][n][jj] + bvv[n]);
            }
        }
    }
}

// ---------------- per-token attention over the HEAD dim ----------------------
// one wave per token; lane = h*8+g computes score[h][g]; softmax over g.
__global__ __launch_bounds__(256) void attn_k(const unsigned short* __restrict__ QKV,
                                              float* __restrict__ out) {
    __shared__ unsigned short sQ[4][HIDDEN];
    __shared__ unsigned short sK[4][HIDDEN];
    __shared__ unsigned short sV[4][HIDDEN];
    __shared__ float sA[4][64];

    const int t = threadIdx.x, lane = t & 63, wave = t >> 6;
    const int token = blockIdx.x * 4 + wave;
    const size_t base = (size_t)token * HIDDEN;
    const unsigned short* q = QKV + base;
    const unsigned short* k = QKV + (size_t)NTOK * HIDDEN + base;
    const unsigned short* v = QKV + 2 * (size_t)NTOK * HIDDEN + base;

#pragma unroll
    for (int i = 0; i < 2; ++i) {
        const int off = (i * 64 + lane) * 8;
        *(u16x8*)&sQ[wave][off] = *(const u16x8*)&q[off];
        *(u16x8*)&sK[wave][off] = *(const u16x8*)&k[off];
        *(u16x8*)&sV[wave][off] = *(const u16x8*)&v[off];
    }
    __syncthreads();

    const int h = lane >> 3, g = lane & 7;
    float sc = 0.f;
    const unsigned short* Qr = &sQ[wave][h * 128];
    const unsigned short* Kr = &sK[wave][g * 128];
#pragma unroll
    for (int d = 0; d < 128; d += 8) {
        u16x8 qv = *(const u16x8*)&Qr[d];
        u16x8 kv = *(const u16x8*)&Kr[d];
#pragma unroll
        for (int j = 0; j < 8; ++j) sc += b2f(qv[j]) * b2f(kv[j]);
    }
    sc *= -0.08838834764831845f;   // NEGATED scale, faithful to source quirk

    float mx = sc;
#pragma unroll
    for (int o = 1; o < 8; o <<= 1) mx = fmaxf(mx, __shfl_xor(mx, o, 64));
    const float e = __expf(sc - mx);
    float sm = e;
#pragma unroll
    for (int o = 1; o < 8; o <<= 1) sm += __shfl_xor(sm, o, 64);
    sA[wave][lane] = e / sm;
    __syncthreads();

    const int c = lane & 7;        // 16-wide d-chunk within head
    float ov[16];
#pragma unroll
    for (int j = 0; j < 16; ++j) ov[j] = 0.f;
    const float* Ar = &sA[wave][h * 8];
#pragma unroll
    for (int gg = 0; gg < 8; ++gg) {
        const float a = Ar[gg];
        const unsigned short* Vr = &sV[wave][gg * 128 + c * 16];
#pragma unroll
        for (int j = 0; j < 16; ++j) ov[j] += a * b2f(Vr[j]);
    }
    float* op = out + base + lane * 16;   // lane*16 == h*128 + c*16
#pragma unroll
    for (int j = 0; j < 16; j += 4) {
        float4 r = make_float4(ov[j], ov[j + 1], ov[j + 2], ov[j + 3]);
        *(float4*)&op[j] = r;
    }
}

extern "C" void kernel_launch(void* const* d_in, const int* in_sizes, int n_in,
                              void* d_out, int out_size, void* d_ws, size_t ws_size,
                              hipStream_t stream) {
    const float* x1 = (const float*)d_in[0];
    const float* Wq = (const float*)d_in[1];
    const float* bq = (const float*)d_in[2];
    const float* Wk = (const float*)d_in[3];
    const float* bk = (const float*)d_in[4];
    const float* Wv = (const float*)d_in[5];
    const float* bv = (const float*)d_in[6];
    float* out = (float*)d_out;

    // workspace layout (bf16 as ushort): Xb | Wb(q,k,v) | QKV  -> 140.5 MB
    unsigned short* Xb  = (unsigned short*)d_ws;
    unsigned short* Wb  = Xb + (size_t)NTOK * HIDDEN;
    unsigned short* QKV = Wb + 3 * (size_t)HIDDEN * HIDDEN;

    cvt_all<<<2048, 256, 0, stream>>>((const float4*)x1, (const float4*)Wq,
                                      (const float4*)Wk, (const float4*)Wv,
                                      (u16x4*)Xb);

    qkv_gemm<<<dim3(1536), 256, 0, stream>>>(Xb, Wb, bq, bk, bv, QKV);

    attn_k<<<NTOK / 4, 256, 0, stream>>>(QKV, out);
}